// Round 12
// baseline (562.903 us; speedup 1.0000x reference)
//
#include <hip/hip_runtime.h>

#define NN 16384
#define EE 262144
#define EMB 300
#define H2 600
#define NL 5
#define BN_EPS 1e-5f
#define KP1 320     // GEMM1 K padded (300->320); also hF16/agg row stride
#define N1  640     // GEMM1 N padded (600->640)
#define KP2 640     // GEMM2 K padded (=N1)
#define N2  320     // GEMM2 N padded (300->320)

typedef unsigned short u16;
typedef unsigned int   u32;
typedef float    f32x4 __attribute__((ext_vector_type(4)));
typedef _Float16 f16x8 __attribute__((ext_vector_type(8)));
typedef _Float16 f16x2 __attribute__((ext_vector_type(2)));
typedef unsigned int u32x4 __attribute__((ext_vector_type(4)));

__device__ inline u16 f2h(float f) {
    _Float16 h = (_Float16)f;
    return __builtin_bit_cast(u16, h);
}
__device__ inline u32 packh2(float x, float y) {
    f16x2 p; p.x = (_Float16)x; p.y = (_Float16)y;
    return __builtin_bit_cast(u32, p);
}

__device__ inline void gload16(const u16* g, u16* l) {
    __builtin_amdgcn_global_load_lds((const __attribute__((address_space(1))) void*)g,
                                     (__attribute__((address_space(3))) void*)l, 16, 0, 0);
}

__device__ inline f16x8 ld_frag(const u16* p) {
    u32x4 v = *reinterpret_cast<const u32x4*>(p);
    return __builtin_bit_cast(f16x8, v);
}

// ---------------- init h (f16, padded rows) ----------------
__global__ void k_init_h(const int* __restrict__ x,
                         const float* __restrict__ ta, const float* __restrict__ td,
                         const float* __restrict__ tc, const float* __restrict__ th,
                         const float* __restrict__ tar, const float* __restrict__ tch,
                         u16* __restrict__ hF) {
    int i = blockIdx.x;
    int j = threadIdx.x;                 // 320 threads
    u16 o = 0;
    if (j < EMB) {
        float v = ta [(size_t)x[i*6+0]*EMB + j] + td [(size_t)x[i*6+1]*EMB + j]
                + tc [(size_t)x[i*6+2]*EMB + j] + th [(size_t)x[i*6+3]*EMB + j]
                + tar[(size_t)x[i*6+4]*EMB + j] + tch[(size_t)x[i*6+5]*EMB + j];
        o = f2h(v);
    }
    hF[(size_t)i*KP1 + j] = o;
}

// ---------------- weight convert+transpose to f16 [n][k] ----------------
__global__ void k_cvt_w1(const float* __restrict__ W1, u16* __restrict__ w1t) {
    int idx = blockIdx.x*256 + threadIdx.x;
    if (idx >= NL*N1*KP1) return;
    int l = idx / (N1*KP1); int rem = idx % (N1*KP1);
    int n = rem / KP1, k = rem % KP1;
    float v = (n < H2 && k < EMB) ? W1[(size_t)l*EMB*H2 + (size_t)k*H2 + n] : 0.f;
    w1t[idx] = f2h(v);
}
__global__ void k_cvt_w2(const float* __restrict__ W2, u16* __restrict__ w2t) {
    int idx = blockIdx.x*256 + threadIdx.x;
    if (idx >= NL*N2*KP2) return;
    int l = idx / (N2*KP2); int rem = idx % (N2*KP2);
    int n = rem / KP2, k = rem % KP2;
    float v = (n < EMB && k < H2) ? W2[(size_t)l*H2*EMB + (size_t)k*EMB + n] : 0.f;
    w2t[idx] = f2h(v);
}

// ---------------- CSR build ----------------
__global__ void k_hist(const int* __restrict__ ei, int* __restrict__ cnt) {
    int e = blockIdx.x * blockDim.x + threadIdx.x;
    if (e < EE) atomicAdd(&cnt[ei[EE + e]], 1);
}

__global__ __launch_bounds__(1024) void k_scan(const int* __restrict__ cnt,
                                               int* __restrict__ row_off,
                                               int* __restrict__ cursor) {
    __shared__ int lds[1024];
    int t = threadIdx.x;
    int base = t * 16;
    int local[16];
    int total = 0;
    #pragma unroll
    for (int i = 0; i < 16; ++i) { local[i] = cnt[base + i]; total += local[i]; }
    lds[t] = total;
    __syncthreads();
    for (int off = 1; off < 1024; off <<= 1) {
        int v = (t >= off) ? lds[t - off] : 0;
        __syncthreads();
        lds[t] += v;
        __syncthreads();
    }
    int run = lds[t] - total;
    #pragma unroll
    for (int i = 0; i < 16; ++i) {
        row_off[base + i] = run;
        cursor[base + i]  = run;
        run += local[i];
    }
    if (t == 0) row_off[NN] = EE;
}

__global__ void k_fill(const int* __restrict__ ei, const int* __restrict__ eattr,
                       int* __restrict__ cursor, int* __restrict__ packed) {
    int e = blockIdx.x * blockDim.x + threadIdx.x;
    if (e >= EE) return;
    int d  = ei[EE + e];
    int s  = ei[e];
    int a0 = eattr[2*e], a1 = eattr[2*e + 1];
    int pos = atomicAdd(&cursor[d], 1);
    packed[pos] = s | ((a0*3 + a1) << 16);
}

// ---------------- per-node gather aggregation (known-good) ----------------
__global__ __launch_bounds__(256) void k_aggregate(const int* __restrict__ row_off,
                                                   const int* __restrict__ packed,
                                                   const u16* __restrict__ hF,
                                                   const float* __restrict__ E1,
                                                   const float* __restrict__ E2,
                                                   u16* __restrict__ agg) {
    __shared__ float comb[10 * EMB];
    int tid = threadIdx.x;
    for (int idx = tid; idx < 10 * EMB; idx += 256) {
        int r = idx / EMB, c = idx % EMB;
        comb[idx] = (r < 9) ? (E1[(r/3)*EMB + c] + E2[(r%3)*EMB + c])
                            : (E1[4*EMB + c]     + E2[0*EMB + c]);
    }
    __syncthreads();

    int wv = tid >> 6, lane = tid & 63;
    int c0 = lane, c1 = lane + 64, c2 = lane + 128;   // u32 chunk indices
    bool a2 = (c2 < 150);          // c0,c1 always active data
    bool w2r = (c2 < 160);         // c2 within row (chunks 150..159 = zero pad)

    int n = blockIdx.x * 4 + wv;
    float x0, y0, x1, y1, x2 = 0.f, y2 = 0.f;
    {   // self-loop init: h[n] + comb[9]
        const u32* hn = (const u32*)(hF + (size_t)n*KP1);
        f16x2 v0 = __builtin_bit_cast(f16x2, hn[c0]);
        f16x2 v1 = __builtin_bit_cast(f16x2, hn[c1]);
        x0 = (float)v0.x + comb[9*EMB + 2*c0];
        y0 = (float)v0.y + comb[9*EMB + 2*c0 + 1];
        x1 = (float)v1.x + comb[9*EMB + 2*c1];
        y1 = (float)v1.y + comb[9*EMB + 2*c1 + 1];
        if (a2) {
            f16x2 v2 = __builtin_bit_cast(f16x2, hn[c2]);
            x2 = (float)v2.x + comb[9*EMB + 2*c2];
            y2 = (float)v2.y + comb[9*EMB + 2*c2 + 1];
        }
    }
    int j0 = row_off[n], j1 = row_off[n+1];
    int j = j0;
    for (; j + 1 < j1; j += 2) {       // 2x unroll for outstanding loads
        int pA = packed[j], pB = packed[j+1];
        const u32* hA = (const u32*)(hF + (size_t)(pA & 0xFFFF)*KP1);
        const u32* hB = (const u32*)(hF + (size_t)(pB & 0xFFFF)*KP1);
        const float* cA = comb + (pA >> 16)*EMB;
        const float* cB = comb + (pB >> 16)*EMB;
        u32 rA0 = hA[c0], rA1 = hA[c1], rB0 = hB[c0], rB1 = hB[c1];
        u32 rA2 = 0, rB2 = 0;
        if (a2) { rA2 = hA[c2]; rB2 = hB[c2]; }
        f16x2 v;
        v = __builtin_bit_cast(f16x2, rA0); x0 += (float)v.x + cA[2*c0]; y0 += (float)v.y + cA[2*c0+1];
        v = __builtin_bit_cast(f16x2, rA1); x1 += (float)v.x + cA[2*c1]; y1 += (float)v.y + cA[2*c1+1];
        v = __builtin_bit_cast(f16x2, rB0); x0 += (float)v.x + cB[2*c0]; y0 += (float)v.y + cB[2*c0+1];
        v = __builtin_bit_cast(f16x2, rB1); x1 += (float)v.x + cB[2*c1]; y1 += (float)v.y + cB[2*c1+1];
        if (a2) {
            v = __builtin_bit_cast(f16x2, rA2); x2 += (float)v.x + cA[2*c2]; y2 += (float)v.y + cA[2*c2+1];
            v = __builtin_bit_cast(f16x2, rB2); x2 += (float)v.x + cB[2*c2]; y2 += (float)v.y + cB[2*c2+1];
        }
    }
    if (j < j1) {
        int pA = packed[j];
        const u32* hA = (const u32*)(hF + (size_t)(pA & 0xFFFF)*KP1);
        const float* cA = comb + (pA >> 16)*EMB;
        f16x2 v;
        v = __builtin_bit_cast(f16x2, hA[c0]); x0 += (float)v.x + cA[2*c0]; y0 += (float)v.y + cA[2*c0+1];
        v = __builtin_bit_cast(f16x2, hA[c1]); x1 += (float)v.x + cA[2*c1]; y1 += (float)v.y + cA[2*c1+1];
        if (a2) {
            v = __builtin_bit_cast(f16x2, hA[c2]); x2 += (float)v.x + cA[2*c2]; y2 += (float)v.y + cA[2*c2+1];
        }
    }
    u32* ao = (u32*)(agg + (size_t)n*KP1);
    ao[c0] = packh2(x0, y0);
    ao[c1] = packh2(x1, y1);
    if (w2r) ao[c2] = a2 ? packh2(x2, y2) : 0u;   // chunks [128,160) only
}

// ---------------- f16 MFMA GEMM: C = op(A @ Bt^T + bias), BK=64, wide BLKN ----
// STATS: fuse per-column BN partial sums (LDS 8-contributor reduce + 1 atomic/col).
// When !STATS and sums!=nullptr, block (0,0) zeroes sums/sumsq for the NEXT
// kernel (stream-ordered; no one reads them until GEMM2's epilogue).
template<int BLKN, bool RELU, bool OUTF16, bool STATS>
__global__ __launch_bounds__(256) void k_mgemm(const u16* __restrict__ A,
                                               const u16* __restrict__ Bt,
                                               const float* __restrict__ bias, int nbias,
                                               void* __restrict__ Cout, int ldc, int ncols,
                                               int KP,
                                               float* __restrict__ sums,
                                               float* __restrict__ sumsq) {
    constexpr int BW = BLKN / 2;
    constexpr int NF = BW / 16;
    __shared__ u16 As[128 * 64];
    __shared__ u16 Bs[BLKN * 64];
    __shared__ float red[STATS ? BLKN * 16 : 1];
    int tid  = threadIdx.x;
    int wv   = tid >> 6, lane = tid & 63;
    int wr   = wv >> 1,  wc   = wv & 1;
    int m0   = blockIdx.y * 128, n0 = blockIdx.x * BLKN;

    if (!STATS && sums != nullptr && blockIdx.x == 0 && blockIdx.y == 0) {
        for (int c = tid; c < EMB; c += 256) { sums[c] = 0.f; sumsq[c] = 0.f; }
    }

    f32x4 acc[4][NF];
    f32x4 zz = {0.f, 0.f, 0.f, 0.f};
    #pragma unroll
    for (int i = 0; i < 4; ++i)
        #pragma unroll
        for (int j = 0; j < NF; ++j) acc[i][j] = zz;

    for (int k0 = 0; k0 < KP; k0 += 64) {
        #pragma unroll
        for (int s = 0; s < 4; ++s) {          // A tile: 128 rows x 8 chunks = 1024
            int c = tid + s*256;
            gload16(A + (size_t)(m0 + (c>>3))*KP + k0 + (c&7)*8, &As[c*8]);
        }
        #pragma unroll
        for (int s = 0; s < BLKN/32; ++s) {    // B tile: BLKN rows x 8 chunks
            int c = tid + s*256;
            gload16(Bt + (size_t)(n0 + (c>>3))*KP + k0 + (c&7)*8, &Bs[c*8]);
        }
        __syncthreads();

        int rA = lane & 15, kq = (lane >> 4) * 8;
        #pragma unroll
        for (int kk = 0; kk < 2; ++kk) {
            f16x8 af[4], bfr[NF];
            #pragma unroll
            for (int mf = 0; mf < 4; ++mf)
                af[mf] = ld_frag(&As[(wr*64 + mf*16 + rA) * 64 + kk*32 + kq]);
            #pragma unroll
            for (int nf = 0; nf < NF; ++nf)
                bfr[nf] = ld_frag(&Bs[(wc*BW + nf*16 + rA) * 64 + kk*32 + kq]);
            #pragma unroll
            for (int mf = 0; mf < 4; ++mf)
                #pragma unroll
                for (int nf = 0; nf < NF; ++nf)
                    acc[mf][nf] = __builtin_amdgcn_mfma_f32_16x16x32_f16(
                        af[mf], bfr[nf], acc[mf][nf], 0, 0, 0);
        }
        __syncthreads();
    }

    // epilogue: C row = (lane>>4)*4 + reg, col = lane&15
    int rq = (lane >> 4) * 4, cn = lane & 15;
    float s1v[NF], s2v[NF];
    #pragma unroll
    for (int nf = 0; nf < NF; ++nf) { s1v[nf] = 0.f; s2v[nf] = 0.f; }
    #pragma unroll
    for (int nf = 0; nf < NF; ++nf) {
        int n = n0 + wc*BW + nf*16 + cn;
        float bv = (n < nbias) ? bias[n] : 0.f;
        #pragma unroll
        for (int mf = 0; mf < 4; ++mf) {
            #pragma unroll
            for (int r = 0; r < 4; ++r) {
                int m = m0 + wr*64 + mf*16 + rq + r;
                float v = acc[mf][nf][r] + bv;
                if (RELU) v = fmaxf(v, 0.f);
                if (STATS) { s1v[nf] += v; s2v[nf] += v*v; }
                if (OUTF16) {
                    ((u16*)Cout)[(size_t)m * ldc + n] = f2h(v);
                } else {
                    if (n < ncols) ((float*)Cout)[(size_t)m * ldc + n] = v;
                }
            }
        }
    }
    if (STATS) {
        int contrib = wr*4 + (lane >> 4);      // 0..7
        #pragma unroll
        for (int nf = 0; nf < NF; ++nf) {
            int cidx = wc*BW + nf*16 + cn;     // 0..BLKN-1
            red[cidx*8 + contrib] = s1v[nf];
            red[BLKN*8 + cidx*8 + contrib] = s2v[nf];
        }
        __syncthreads();
        for (int cc = tid; cc < BLKN; cc += 256) {   // BLKN may exceed 256
            int n = n0 + cc;
            if (n < nbias) {
                float a = 0.f, b = 0.f;
                #pragma unroll
                for (int q = 0; q < 8; ++q) {
                    a += red[cc*8 + q];
                    b += red[BLKN*8 + cc*8 + q];
                }
                atomicAdd(&sums[n], a);
                atomicAdd(&sumsq[n], b);
            }
        }
    }
}

// ---------------- BN apply (mu/rs recomputed per block from sums/sumsq) ----------------
#define CH 75   // float4 chunks per 300-channel row

// layers 0..3: normalize + affine + ReLU -> f16 padded hF (pad cols never read)
__global__ __launch_bounds__(256) void k_bnapply_f16(
        const float* __restrict__ hP, const float* __restrict__ sums,
        const float* __restrict__ sumsq, const float* __restrict__ gamma,
        const float* __restrict__ beta, u16* __restrict__ hF) {
    __shared__ float smu[EMB], sga[EMB], sbe[EMB];
    int tid = threadIdx.x;
    for (int c = tid; c < EMB; c += 256) {
        float m = sums[c] * (1.f/NN);
        float v = sumsq[c] * (1.f/NN) - m*m;
        smu[c] = m;
        sga[c] = rsqrtf(v + BN_EPS) * gamma[c];
        sbe[c] = beta[c];
    }
    __syncthreads();
    const int total = NN * CH;
    for (int idx = blockIdx.x*256 + tid; idx < total; idx += gridDim.x*256) {
        int r = idx / CH, ch = idx - r*CH;
        int c = ch*4;
        f32x4 v = *(const f32x4*)(hP + (size_t)r*EMB + c);
        float o0 = fmaxf((v[0] - smu[c  ])*sga[c  ] + sbe[c  ], 0.f);
        float o1 = fmaxf((v[1] - smu[c+1])*sga[c+1] + sbe[c+1], 0.f);
        float o2 = fmaxf((v[2] - smu[c+2])*sga[c+2] + sbe[c+2], 0.f);
        float o3 = fmaxf((v[3] - smu[c+3])*sga[c+3] + sbe[c+3], 0.f);
        u32* dst = (u32*)(hF + (size_t)r*KP1) + ch*2;
        dst[0] = packh2(o0, o1);
        dst[1] = packh2(o2, o3);
    }
}

// last layer: normalize + affine (no ReLU) -> f32 out
__global__ __launch_bounds__(256) void k_bnapply_f32(
        const float* __restrict__ hP, const float* __restrict__ sums,
        const float* __restrict__ sumsq, const float* __restrict__ gamma,
        const float* __restrict__ beta, float* __restrict__ out) {
    __shared__ float smu[EMB], sga[EMB], sbe[EMB];
    int tid = threadIdx.x;
    for (int c = tid; c < EMB; c += 256) {
        float m = sums[c] * (1.f/NN);
        float v = sumsq[c] * (1.f/NN) - m*m;
        smu[c] = m;
        sga[c] = rsqrtf(v + BN_EPS) * gamma[c];
        sbe[c] = beta[c];
    }
    __syncthreads();
    const int total = NN * CH;
    for (int idx = blockIdx.x*256 + tid; idx < total; idx += gridDim.x*256) {
        int r = idx / CH, ch = idx - r*CH;
        int c = ch*4;
        f32x4 v = *(const f32x4*)(hP + (size_t)r*EMB + c);
        f32x4 o;
        o[0] = (v[0] - smu[c  ])*sga[c  ] + sbe[c  ];
        o[1] = (v[1] - smu[c+1])*sga[c+1] + sbe[c+1];
        o[2] = (v[2] - smu[c+2])*sga[c+2] + sbe[c+2];
        o[3] = (v[3] - smu[c+3])*sga[c+3] + sbe[c+3];
        *(f32x4*)(out + (size_t)r*EMB + c) = o;
    }
}

extern "C" void kernel_launch(void* const* d_in, const int* in_sizes, int n_in,
                              void* d_out, int out_size, void* d_ws, size_t ws_size,
                              hipStream_t stream) {
    const int*   x     = (const int*)d_in[0];
    const int*   ei    = (const int*)d_in[1];
    const int*   eattr = (const int*)d_in[2];
    const float* ta    = (const float*)d_in[3];
    const float* td    = (const float*)d_in[4];
    const float* tc    = (const float*)d_in[5];
    const float* th    = (const float*)d_in[6];
    const float* tar   = (const float*)d_in[7];
    const float* tch   = (const float*)d_in[8];
    const float* W1    = (const float*)d_in[9];
    const float* b1    = (const float*)d_in[10];
    const float* W2    = (const float*)d_in[11];
    const float* b2    = (const float*)d_in[12];
    const float* ee1   = (const float*)d_in[13];
    const float* ee2   = (const float*)d_in[14];
    const float* gam   = (const float*)d_in[15];
    const float* bet   = (const float*)d_in[16];
    float* out = (float*)d_out;

    char* ws = (char*)d_ws;
    float* hP   = (float*)ws;                         ws += (size_t)NN*EMB*4;   // pre-BN h (f32)
    u16*   hF   = (u16*)ws;                           ws += (size_t)NN*KP1*2;   // post-BN h (f16)
    u16*   aggF = (u16*)ws;                           ws += (size_t)NN*KP1*2;
    u16*   t    = (u16*)ws;                           ws += (size_t)NN*N1*2;
    u16*   w1t  = (u16*)ws;                           ws += (size_t)NL*N1*KP1*2;
    u16*   w2t  = (u16*)ws;                           ws += (size_t)NL*N2*KP2*2;
    float* stat = (float*)ws;                         ws += 4096;
    int*   cnt  = (int*)ws;                           ws += (size_t)NN*4;
    int*   row_off = (int*)ws;                        ws += (size_t)(NN+1)*4 + 60;
    int*   cursor  = (int*)ws;                        ws += (size_t)NN*4;
    int*   packed  = (int*)ws;
    float* sums = stat, *sumsq = stat+300;

    // ---- once per call: weight f16 transpose, CSR build, init h ----
    k_cvt_w1<<<(NL*N1*KP1 + 255)/256, 256, 0, stream>>>(W1, w1t);
    k_cvt_w2<<<(NL*N2*KP2 + 255)/256, 256, 0, stream>>>(W2, w2t);
    hipMemsetAsync(cnt, 0, (size_t)NN*4, stream);
    k_hist<<<EE/256, 256, 0, stream>>>(ei, cnt);
    k_scan<<<1, 1024, 0, stream>>>(cnt, row_off, cursor);
    k_fill<<<EE/256, 256, 0, stream>>>(ei, eattr, cursor, packed);
    k_init_h<<<NN, KP1, 0, stream>>>(x, ta, td, tc, th, tar, tch, hF);

    for (int l = 0; l < NL; ++l) {
        k_aggregate<<<4096, 256, 0, stream>>>(row_off, packed, hF,
                                              ee1 + (size_t)l*6*EMB,
                                              ee2 + (size_t)l*3*EMB, aggF);
        // GEMM1: 128x320 tiles, grid (2,128); block (0,0) also zeroes stats.
        k_mgemm<320, true, true, false><<<dim3(N1/320, NN/128), 256, 0, stream>>>(
            aggF, w1t + (size_t)l*N1*KP1, b1 + (size_t)l*H2, H2,
            t, N1, N1, KP1, sums, sumsq);
        // GEMM2: 128x320 tiles, grid (1,128); fused BN stats.
        k_mgemm<320, false, false, true><<<dim3(N2/320, NN/128), 256, 0, stream>>>(
            t, w2t + (size_t)l*N2*KP2, b2 + (size_t)l*EMB, EMB,
            hP, EMB, EMB, KP2, sums, sumsq);
        if (l < NL-1)
            k_bnapply_f16<<<2048, 256, 0, stream>>>(hP, sums, sumsq,
                                                    gam + (size_t)l*EMB, bet + (size_t)l*EMB, hF);
        else
            k_bnapply_f32<<<2048, 256, 0, stream>>>(hP, sums, sumsq,
                                                    gam + (size_t)l*EMB, bet + (size_t)l*EMB, out);
    }
}

// Round 13
// 483.851 us; speedup vs baseline: 1.1634x; 1.1634x over previous
//
#include <hip/hip_runtime.h>

#define NN 16384
#define EE 262144
#define EMB 300
#define H2 600
#define NL 5
#define BN_EPS 1e-5f
#define KP1 320     // GEMM1 K padded (300->320); also hF16/agg row stride
#define N1  640     // GEMM1 N padded (600->640)
#define KP2 640     // GEMM2 K padded (=N1)
#define N2  320     // GEMM2 N padded (300->320)

typedef unsigned short u16;
typedef unsigned int   u32;
typedef float    f32x4 __attribute__((ext_vector_type(4)));
typedef _Float16 f16x8 __attribute__((ext_vector_type(8)));
typedef _Float16 f16x2 __attribute__((ext_vector_type(2)));
typedef unsigned int u32x4 __attribute__((ext_vector_type(4)));

__device__ inline u16 f2h(float f) {
    _Float16 h = (_Float16)f;
    return __builtin_bit_cast(u16, h);
}
__device__ inline u32 packh2(float x, float y) {
    f16x2 p; p.x = (_Float16)x; p.y = (_Float16)y;
    return __builtin_bit_cast(u32, p);
}

__device__ inline void gload16(const u16* g, u16* l) {
    __builtin_amdgcn_global_load_lds((const __attribute__((address_space(1))) void*)g,
                                     (__attribute__((address_space(3))) void*)l, 16, 0, 0);
}

__device__ inline f16x8 ld_frag(const u16* p) {
    u32x4 v = *reinterpret_cast<const u32x4*>(p);
    return __builtin_bit_cast(f16x8, v);
}

// ---------------- init h (f16, padded rows) ----------------
__global__ void k_init_h(const int* __restrict__ x,
                         const float* __restrict__ ta, const float* __restrict__ td,
                         const float* __restrict__ tc, const float* __restrict__ th,
                         const float* __restrict__ tar, const float* __restrict__ tch,
                         u16* __restrict__ hF) {
    int i = blockIdx.x;
    int j = threadIdx.x;                 // 320 threads
    u16 o = 0;
    if (j < EMB) {
        float v = ta [(size_t)x[i*6+0]*EMB + j] + td [(size_t)x[i*6+1]*EMB + j]
                + tc [(size_t)x[i*6+2]*EMB + j] + th [(size_t)x[i*6+3]*EMB + j]
                + tar[(size_t)x[i*6+4]*EMB + j] + tch[(size_t)x[i*6+5]*EMB + j];
        o = f2h(v);
    }
    hF[(size_t)i*KP1 + j] = o;
}

// ---------------- weight convert+transpose to f16 [n][k] ----------------
__global__ void k_cvt_w1(const float* __restrict__ W1, u16* __restrict__ w1t) {
    int idx = blockIdx.x*256 + threadIdx.x;
    if (idx >= NL*N1*KP1) return;
    int l = idx / (N1*KP1); int rem = idx % (N1*KP1);
    int n = rem / KP1, k = rem % KP1;
    float v = (n < H2 && k < EMB) ? W1[(size_t)l*EMB*H2 + (size_t)k*H2 + n] : 0.f;
    w1t[idx] = f2h(v);
}
__global__ void k_cvt_w2(const float* __restrict__ W2, u16* __restrict__ w2t) {
    int idx = blockIdx.x*256 + threadIdx.x;
    if (idx >= NL*N2*KP2) return;
    int l = idx / (N2*KP2); int rem = idx % (N2*KP2);
    int n = rem / KP2, k = rem % KP2;
    float v = (n < EMB && k < H2) ? W2[(size_t)l*H2*EMB + (size_t)k*EMB + n] : 0.f;
    w2t[idx] = f2h(v);
}

// ---------------- CSR build ----------------
__global__ void k_hist(const int* __restrict__ ei, int* __restrict__ cnt) {
    int e = blockIdx.x * blockDim.x + threadIdx.x;
    if (e < EE) atomicAdd(&cnt[ei[EE + e]], 1);
}

__global__ __launch_bounds__(1024) void k_scan(const int* __restrict__ cnt,
                                               int* __restrict__ row_off,
                                               int* __restrict__ cursor) {
    __shared__ int lds[1024];
    int t = threadIdx.x;
    int base = t * 16;
    int local[16];
    int total = 0;
    #pragma unroll
    for (int i = 0; i < 16; ++i) { local[i] = cnt[base + i]; total += local[i]; }
    lds[t] = total;
    __syncthreads();
    for (int off = 1; off < 1024; off <<= 1) {
        int v = (t >= off) ? lds[t - off] : 0;
        __syncthreads();
        lds[t] += v;
        __syncthreads();
    }
    int run = lds[t] - total;
    #pragma unroll
    for (int i = 0; i < 16; ++i) {
        row_off[base + i] = run;
        cursor[base + i]  = run;
        run += local[i];
    }
    if (t == 0) row_off[NN] = EE;
}

__global__ void k_fill(const int* __restrict__ ei, const int* __restrict__ eattr,
                       int* __restrict__ cursor, int* __restrict__ packed) {
    int e = blockIdx.x * blockDim.x + threadIdx.x;
    if (e >= EE) return;
    int d  = ei[EE + e];
    int s  = ei[e];
    int a0 = eattr[2*e], a1 = eattr[2*e + 1];
    int pos = atomicAdd(&cursor[d], 1);
    packed[pos] = s | ((a0*3 + a1) << 16);
}

// ---------------- per-node gather aggregation (round-6/9 body, 4x j-unroll) ----------------
__global__ __launch_bounds__(256) void k_aggregate(const int* __restrict__ row_off,
                                                   const int* __restrict__ packed,
                                                   const u16* __restrict__ hF,
                                                   const float* __restrict__ E1,
                                                   const float* __restrict__ E2,
                                                   u16* __restrict__ agg) {
    __shared__ float comb[10 * EMB];
    int tid = threadIdx.x;
    for (int idx = tid; idx < 10 * EMB; idx += 256) {
        int r = idx / EMB, c = idx % EMB;
        comb[idx] = (r < 9) ? (E1[(r/3)*EMB + c] + E2[(r%3)*EMB + c])
                            : (E1[4*EMB + c]     + E2[0*EMB + c]);
    }
    __syncthreads();

    int wv = tid >> 6, lane = tid & 63;
    int c0 = lane, c1 = lane + 64, c2 = lane + 128;   // u32 chunk indices
    bool a2 = (c2 < 150);          // c0,c1 always active data
    bool w2r = (c2 < 160);         // c2 within row (chunks 150..159 = zero pad)

    int n = blockIdx.x * 4 + wv;
    float x0, y0, x1, y1, x2 = 0.f, y2 = 0.f;
    {   // self-loop init: h[n] + comb[9]
        const u32* hn = (const u32*)(hF + (size_t)n*KP1);
        f16x2 v0 = __builtin_bit_cast(f16x2, hn[c0]);
        f16x2 v1 = __builtin_bit_cast(f16x2, hn[c1]);
        x0 = (float)v0.x + comb[9*EMB + 2*c0];
        y0 = (float)v0.y + comb[9*EMB + 2*c0 + 1];
        x1 = (float)v1.x + comb[9*EMB + 2*c1];
        y1 = (float)v1.y + comb[9*EMB + 2*c1 + 1];
        if (a2) {
            f16x2 v2 = __builtin_bit_cast(f16x2, hn[c2]);
            x2 = (float)v2.x + comb[9*EMB + 2*c2];
            y2 = (float)v2.y + comb[9*EMB + 2*c2 + 1];
        }
    }
    int j0 = row_off[n], j1 = row_off[n+1];
    int j = j0;
    for (; j + 3 < j1; j += 4) {       // 4x unroll: more outstanding gathers
        int pA = packed[j],   pB = packed[j+1];
        int pC = packed[j+2], pD = packed[j+3];
        const u32* hA = (const u32*)(hF + (size_t)(pA & 0xFFFF)*KP1);
        const u32* hB = (const u32*)(hF + (size_t)(pB & 0xFFFF)*KP1);
        const u32* hC = (const u32*)(hF + (size_t)(pC & 0xFFFF)*KP1);
        const u32* hD = (const u32*)(hF + (size_t)(pD & 0xFFFF)*KP1);
        const float* cA = comb + (pA >> 16)*EMB;
        const float* cB = comb + (pB >> 16)*EMB;
        const float* cC = comb + (pC >> 16)*EMB;
        const float* cD = comb + (pD >> 16)*EMB;
        u32 rA0 = hA[c0], rA1 = hA[c1], rB0 = hB[c0], rB1 = hB[c1];
        u32 rC0 = hC[c0], rC1 = hC[c1], rD0 = hD[c0], rD1 = hD[c1];
        u32 rA2 = 0, rB2 = 0, rC2 = 0, rD2 = 0;
        if (a2) { rA2 = hA[c2]; rB2 = hB[c2]; rC2 = hC[c2]; rD2 = hD[c2]; }
        f16x2 v;
        v = __builtin_bit_cast(f16x2, rA0); x0 += (float)v.x + cA[2*c0]; y0 += (float)v.y + cA[2*c0+1];
        v = __builtin_bit_cast(f16x2, rA1); x1 += (float)v.x + cA[2*c1]; y1 += (float)v.y + cA[2*c1+1];
        v = __builtin_bit_cast(f16x2, rB0); x0 += (float)v.x + cB[2*c0]; y0 += (float)v.y + cB[2*c0+1];
        v = __builtin_bit_cast(f16x2, rB1); x1 += (float)v.x + cB[2*c1]; y1 += (float)v.y + cB[2*c1+1];
        v = __builtin_bit_cast(f16x2, rC0); x0 += (float)v.x + cC[2*c0]; y0 += (float)v.y + cC[2*c0+1];
        v = __builtin_bit_cast(f16x2, rC1); x1 += (float)v.x + cC[2*c1]; y1 += (float)v.y + cC[2*c1+1];
        v = __builtin_bit_cast(f16x2, rD0); x0 += (float)v.x + cD[2*c0]; y0 += (float)v.y + cD[2*c0+1];
        v = __builtin_bit_cast(f16x2, rD1); x1 += (float)v.x + cD[2*c1]; y1 += (float)v.y + cD[2*c1+1];
        if (a2) {
            v = __builtin_bit_cast(f16x2, rA2); x2 += (float)v.x + cA[2*c2]; y2 += (float)v.y + cA[2*c2+1];
            v = __builtin_bit_cast(f16x2, rB2); x2 += (float)v.x + cB[2*c2]; y2 += (float)v.y + cB[2*c2+1];
            v = __builtin_bit_cast(f16x2, rC2); x2 += (float)v.x + cC[2*c2]; y2 += (float)v.y + cC[2*c2+1];
            v = __builtin_bit_cast(f16x2, rD2); x2 += (float)v.x + cD[2*c2]; y2 += (float)v.y + cD[2*c2+1];
        }
    }
    for (; j < j1; ++j) {
        int pA = packed[j];
        const u32* hA = (const u32*)(hF + (size_t)(pA & 0xFFFF)*KP1);
        const float* cA = comb + (pA >> 16)*EMB;
        f16x2 v;
        v = __builtin_bit_cast(f16x2, hA[c0]); x0 += (float)v.x + cA[2*c0]; y0 += (float)v.y + cA[2*c0+1];
        v = __builtin_bit_cast(f16x2, hA[c1]); x1 += (float)v.x + cA[2*c1]; y1 += (float)v.y + cA[2*c1+1];
        if (a2) {
            v = __builtin_bit_cast(f16x2, hA[c2]); x2 += (float)v.x + cA[2*c2]; y2 += (float)v.y + cA[2*c2+1];
        }
    }
    u32* ao = (u32*)(agg + (size_t)n*KP1);
    ao[c0] = packh2(x0, y0);
    ao[c1] = packh2(x1, y1);
    if (w2r) ao[c2] = a2 ? packh2(x2, y2) : 0u;   // chunks [128,160) only
}

// ---------------- f16 MFMA GEMM: C = op(A @ Bt^T + bias), BK=64 ----------------
// STATS: fuse per-column BN partial sums (LDS 8-contributor reduce + 1 atomic/col).
// When !STATS and sums!=nullptr, block (0,0) zeroes sums/sumsq for the NEXT
// kernel (stream-ordered; nothing reads them until GEMM2's epilogue).
template<int BLKN, bool RELU, bool OUTF16, bool STATS>
__global__ __launch_bounds__(256) void k_mgemm(const u16* __restrict__ A,
                                               const u16* __restrict__ Bt,
                                               const float* __restrict__ bias, int nbias,
                                               void* __restrict__ Cout, int ldc, int ncols,
                                               int KP,
                                               float* __restrict__ sums,
                                               float* __restrict__ sumsq) {
    constexpr int BW = BLKN / 2;
    constexpr int NF = BW / 16;
    __shared__ u16 As[128 * 64];
    __shared__ u16 Bs[BLKN * 64];
    __shared__ float red[STATS ? BLKN * 16 : 1];
    int tid  = threadIdx.x;
    int wv   = tid >> 6, lane = tid & 63;
    int wr   = wv >> 1,  wc   = wv & 1;
    int m0   = blockIdx.y * 128, n0 = blockIdx.x * BLKN;

    if (!STATS && sums != nullptr && blockIdx.x == 0 && blockIdx.y == 0) {
        for (int c = tid; c < EMB; c += 256) { sums[c] = 0.f; sumsq[c] = 0.f; }
    }

    f32x4 acc[4][NF];
    f32x4 zz = {0.f, 0.f, 0.f, 0.f};
    #pragma unroll
    for (int i = 0; i < 4; ++i)
        #pragma unroll
        for (int j = 0; j < NF; ++j) acc[i][j] = zz;

    for (int k0 = 0; k0 < KP; k0 += 64) {
        #pragma unroll
        for (int s = 0; s < 4; ++s) {          // A tile: 128 rows x 8 chunks = 1024
            int c = tid + s*256;
            gload16(A + (size_t)(m0 + (c>>3))*KP + k0 + (c&7)*8, &As[c*8]);
        }
        #pragma unroll
        for (int s = 0; s < BLKN/32; ++s) {    // B tile: BLKN rows x 8 chunks
            int c = tid + s*256;
            gload16(Bt + (size_t)(n0 + (c>>3))*KP + k0 + (c&7)*8, &Bs[c*8]);
        }
        __syncthreads();

        int rA = lane & 15, kq = (lane >> 4) * 8;
        #pragma unroll
        for (int kk = 0; kk < 2; ++kk) {
            f16x8 af[4], bfr[NF];
            #pragma unroll
            for (int mf = 0; mf < 4; ++mf)
                af[mf] = ld_frag(&As[(wr*64 + mf*16 + rA) * 64 + kk*32 + kq]);
            #pragma unroll
            for (int nf = 0; nf < NF; ++nf)
                bfr[nf] = ld_frag(&Bs[(wc*BW + nf*16 + rA) * 64 + kk*32 + kq]);
            #pragma unroll
            for (int mf = 0; mf < 4; ++mf)
                #pragma unroll
                for (int nf = 0; nf < NF; ++nf)
                    acc[mf][nf] = __builtin_amdgcn_mfma_f32_16x16x32_f16(
                        af[mf], bfr[nf], acc[mf][nf], 0, 0, 0);
        }
        __syncthreads();
    }

    // epilogue: C row = (lane>>4)*4 + reg, col = lane&15
    int rq = (lane >> 4) * 4, cn = lane & 15;
    float s1v[NF], s2v[NF];
    #pragma unroll
    for (int nf = 0; nf < NF; ++nf) { s1v[nf] = 0.f; s2v[nf] = 0.f; }
    #pragma unroll
    for (int nf = 0; nf < NF; ++nf) {
        int n = n0 + wc*BW + nf*16 + cn;
        float bv = (n < nbias) ? bias[n] : 0.f;
        #pragma unroll
        for (int mf = 0; mf < 4; ++mf) {
            #pragma unroll
            for (int r = 0; r < 4; ++r) {
                int m = m0 + wr*64 + mf*16 + rq + r;
                float v = acc[mf][nf][r] + bv;
                if (RELU) v = fmaxf(v, 0.f);
                if (STATS) { s1v[nf] += v; s2v[nf] += v*v; }
                if (OUTF16) {
                    ((u16*)Cout)[(size_t)m * ldc + n] = f2h(v);
                } else {
                    if (n < ncols) ((float*)Cout)[(size_t)m * ldc + n] = v;
                }
            }
        }
    }
    if (STATS) {
        int contrib = wr*4 + (lane >> 4);      // 0..7
        #pragma unroll
        for (int nf = 0; nf < NF; ++nf) {
            int cidx = wc*BW + nf*16 + cn;     // 0..BLKN-1
            red[cidx*8 + contrib] = s1v[nf];
            red[BLKN*8 + cidx*8 + contrib] = s2v[nf];
        }
        __syncthreads();
        for (int cc = tid; cc < BLKN; cc += 256) {
            int n = n0 + cc;
            if (n < nbias) {
                float a = 0.f, b = 0.f;
                #pragma unroll
                for (int q = 0; q < 8; ++q) {
                    a += red[cc*8 + q];
                    b += red[BLKN*8 + cc*8 + q];
                }
                atomicAdd(&sums[n], a);
                atomicAdd(&sumsq[n], b);
            }
        }
    }
}

// ---------------- BN apply (mu/rs recomputed per block from sums/sumsq) ----------------
#define CH 75   // float4 chunks per 300-channel row

// layers 0..3: normalize + affine + ReLU -> f16 padded hF (pad cols never read)
__global__ __launch_bounds__(256) void k_bnapply_f16(
        const float* __restrict__ hP, const float* __restrict__ sums,
        const float* __restrict__ sumsq, const float* __restrict__ gamma,
        const float* __restrict__ beta, u16* __restrict__ hF) {
    __shared__ float smu[EMB], sga[EMB], sbe[EMB];
    int tid = threadIdx.x;
    for (int c = tid; c < EMB; c += 256) {
        float m = sums[c] * (1.f/NN);
        float v = sumsq[c] * (1.f/NN) - m*m;
        smu[c] = m;
        sga[c] = rsqrtf(v + BN_EPS) * gamma[c];
        sbe[c] = beta[c];
    }
    __syncthreads();
    const int total = NN * CH;
    for (int idx = blockIdx.x*256 + tid; idx < total; idx += gridDim.x*256) {
        int r = idx / CH, ch = idx - r*CH;
        int c = ch*4;
        f32x4 v = *(const f32x4*)(hP + (size_t)r*EMB + c);
        float o0 = fmaxf((v[0] - smu[c  ])*sga[c  ] + sbe[c  ], 0.f);
        float o1 = fmaxf((v[1] - smu[c+1])*sga[c+1] + sbe[c+1], 0.f);
        float o2 = fmaxf((v[2] - smu[c+2])*sga[c+2] + sbe[c+2], 0.f);
        float o3 = fmaxf((v[3] - smu[c+3])*sga[c+3] + sbe[c+3], 0.f);
        u32* dst = (u32*)(hF + (size_t)r*KP1) + ch*2;
        dst[0] = packh2(o0, o1);
        dst[1] = packh2(o2, o3);
    }
}

// last layer: normalize + affine (no ReLU) -> f32 out
__global__ __launch_bounds__(256) void k_bnapply_f32(
        const float* __restrict__ hP, const float* __restrict__ sums,
        const float* __restrict__ sumsq, const float* __restrict__ gamma,
        const float* __restrict__ beta, float* __restrict__ out) {
    __shared__ float smu[EMB], sga[EMB], sbe[EMB];
    int tid = threadIdx.x;
    for (int c = tid; c < EMB; c += 256) {
        float m = sums[c] * (1.f/NN);
        float v = sumsq[c] * (1.f/NN) - m*m;
        smu[c] = m;
        sga[c] = rsqrtf(v + BN_EPS) * gamma[c];
        sbe[c] = beta[c];
    }
    __syncthreads();
    const int total = NN * CH;
    for (int idx = blockIdx.x*256 + tid; idx < total; idx += gridDim.x*256) {
        int r = idx / CH, ch = idx - r*CH;
        int c = ch*4;
        f32x4 v = *(const f32x4*)(hP + (size_t)r*EMB + c);
        f32x4 o;
        o[0] = (v[0] - smu[c  ])*sga[c  ] + sbe[c  ];
        o[1] = (v[1] - smu[c+1])*sga[c+1] + sbe[c+1];
        o[2] = (v[2] - smu[c+2])*sga[c+2] + sbe[c+2];
        o[3] = (v[3] - smu[c+3])*sga[c+3] + sbe[c+3];
        *(f32x4*)(out + (size_t)r*EMB + c) = o;
    }
}

extern "C" void kernel_launch(void* const* d_in, const int* in_sizes, int n_in,
                              void* d_out, int out_size, void* d_ws, size_t ws_size,
                              hipStream_t stream) {
    const int*   x     = (const int*)d_in[0];
    const int*   ei    = (const int*)d_in[1];
    const int*   eattr = (const int*)d_in[2];
    const float* ta    = (const float*)d_in[3];
    const float* td    = (const float*)d_in[4];
    const float* tc    = (const float*)d_in[5];
    const float* th    = (const float*)d_in[6];
    const float* tar   = (const float*)d_in[7];
    const float* tch   = (const float*)d_in[8];
    const float* W1    = (const float*)d_in[9];
    const float* b1    = (const float*)d_in[10];
    const float* W2    = (const float*)d_in[11];
    const float* b2    = (const float*)d_in[12];
    const float* ee1   = (const float*)d_in[13];
    const float* ee2   = (const float*)d_in[14];
    const float* gam   = (const float*)d_in[15];
    const float* bet   = (const float*)d_in[16];
    float* out = (float*)d_out;

    char* ws = (char*)d_ws;
    float* hP   = (float*)ws;                         ws += (size_t)NN*EMB*4;   // pre-BN h (f32)
    u16*   hF   = (u16*)ws;                           ws += (size_t)NN*KP1*2;   // post-BN h (f16)
    u16*   aggF = (u16*)ws;                           ws += (size_t)NN*KP1*2;
    u16*   t    = (u16*)ws;                           ws += (size_t)NN*N1*2;
    u16*   w1t  = (u16*)ws;                           ws += (size_t)NL*N1*KP1*2;
    u16*   w2t  = (u16*)ws;                           ws += (size_t)NL*N2*KP2*2;
    float* stat = (float*)ws;                         ws += 4096;
    int*   cnt  = (int*)ws;                           ws += (size_t)NN*4;
    int*   row_off = (int*)ws;                        ws += (size_t)(NN+1)*4 + 60;
    int*   cursor  = (int*)ws;                        ws += (size_t)NN*4;
    int*   packed  = (int*)ws;
    float* sums = stat, *sumsq = stat+300;

    // ---- once per call: weight f16 transpose, CSR build, init h ----
    k_cvt_w1<<<(NL*N1*KP1 + 255)/256, 256, 0, stream>>>(W1, w1t);
    k_cvt_w2<<<(NL*N2*KP2 + 255)/256, 256, 0, stream>>>(W2, w2t);
    hipMemsetAsync(cnt, 0, (size_t)NN*4, stream);
    k_hist<<<EE/256, 256, 0, stream>>>(ei, cnt);
    k_scan<<<1, 1024, 0, stream>>>(cnt, row_off, cursor);
    k_fill<<<EE/256, 256, 0, stream>>>(ei, eattr, cursor, packed);
    k_init_h<<<NN, KP1, 0, stream>>>(x, ta, td, tc, th, tar, tch, hF);

    for (int l = 0; l < NL; ++l) {
        k_aggregate<<<4096, 256, 0, stream>>>(row_off, packed, hF,
                                              ee1 + (size_t)l*6*EMB,
                                              ee2 + (size_t)l*3*EMB, aggF);
        // GEMM1: 128x128 tiles, grid (5,128); block (0,0) also zeroes stats.
        k_mgemm<128, true, true, false><<<dim3(N1/128, NN/128), 256, 0, stream>>>(
            aggF, w1t + (size_t)l*N1*KP1, b1 + (size_t)l*H2, H2,
            t, N1, N1, KP1, sums, sumsq);
        // GEMM2: 128x64 tiles, grid (5,128); fused BN stats.
        k_mgemm<64, false, false, true><<<dim3(N2/64, NN/128), 256, 0, stream>>>(
            t, w2t + (size_t)l*N2*KP2, b2 + (size_t)l*EMB, EMB,
            hP, EMB, EMB, KP2, sums, sumsq);
        if (l < NL-1)
            k_bnapply_f16<<<2048, 256, 0, stream>>>(hP, sums, sumsq,
                                                    gam + (size_t)l*EMB, bet + (size_t)l*EMB, hF);
        else
            k_bnapply_f32<<<2048, 256, 0, stream>>>(hP, sums, sumsq,
                                                    gam + (size_t)l*EMB, bet + (size_t)l*EMB, out);
    }
}

// Round 14
// 455.608 us; speedup vs baseline: 1.2355x; 1.0620x over previous
//
#include <hip/hip_runtime.h>

#define NN 16384
#define EE 262144
#define EMB 300
#define H2 600
#define NL 5
#define BN_EPS 1e-5f
#define KP1 320     // GEMM1 K padded (300->320); also hF16/agg row stride
#define N1  640     // GEMM1 N padded (600->640)
#define KP2 640     // GEMM2 K padded (=N1)
#define N2  320     // GEMM2 N padded (300->320)

typedef unsigned short u16;
typedef unsigned int   u32;
typedef float    f32x4 __attribute__((ext_vector_type(4)));
typedef float    f32x2 __attribute__((ext_vector_type(2)));
typedef _Float16 f16x8 __attribute__((ext_vector_type(8)));
typedef _Float16 f16x2 __attribute__((ext_vector_type(2)));
typedef unsigned int u32x4 __attribute__((ext_vector_type(4)));

__device__ inline u16 f2h(float f) {
    _Float16 h = (_Float16)f;
    return __builtin_bit_cast(u16, h);
}
__device__ inline u32 packh2(float x, float y) {
    f16x2 p; p.x = (_Float16)x; p.y = (_Float16)y;
    return __builtin_bit_cast(u32, p);
}

__device__ inline void gload16(const u16* g, u16* l) {
    __builtin_amdgcn_global_load_lds((const __attribute__((address_space(1))) void*)g,
                                     (__attribute__((address_space(3))) void*)l, 16, 0, 0);
}

__device__ inline f16x8 ld_frag(const u16* p) {
    u32x4 v = *reinterpret_cast<const u32x4*>(p);
    return __builtin_bit_cast(f16x8, v);
}

// ---------------- init h (f16, padded rows) ----------------
__global__ void k_init_h(const int* __restrict__ x,
                         const float* __restrict__ ta, const float* __restrict__ td,
                         const float* __restrict__ tc, const float* __restrict__ th,
                         const float* __restrict__ tar, const float* __restrict__ tch,
                         u16* __restrict__ hF) {
    int i = blockIdx.x;
    int j = threadIdx.x;                 // 320 threads
    u16 o = 0;
    if (j < EMB) {
        float v = ta [(size_t)x[i*6+0]*EMB + j] + td [(size_t)x[i*6+1]*EMB + j]
                + tc [(size_t)x[i*6+2]*EMB + j] + th [(size_t)x[i*6+3]*EMB + j]
                + tar[(size_t)x[i*6+4]*EMB + j] + tch[(size_t)x[i*6+5]*EMB + j];
        o = f2h(v);
    }
    hF[(size_t)i*KP1 + j] = o;
}

// ---------------- weight convert+transpose to f16 [n][k] ----------------
__global__ void k_cvt_w1(const float* __restrict__ W1, u16* __restrict__ w1t) {
    int idx = blockIdx.x*256 + threadIdx.x;
    if (idx >= NL*N1*KP1) return;
    int l = idx / (N1*KP1); int rem = idx % (N1*KP1);
    int n = rem / KP1, k = rem % KP1;
    float v = (n < H2 && k < EMB) ? W1[(size_t)l*EMB*H2 + (size_t)k*H2 + n] : 0.f;
    w1t[idx] = f2h(v);
}
__global__ void k_cvt_w2(const float* __restrict__ W2, u16* __restrict__ w2t) {
    int idx = blockIdx.x*256 + threadIdx.x;
    if (idx >= NL*N2*KP2) return;
    int l = idx / (N2*KP2); int rem = idx % (N2*KP2);
    int n = rem / KP2, k = rem % KP2;
    float v = (n < EMB && k < H2) ? W2[(size_t)l*H2*EMB + (size_t)k*EMB + n] : 0.f;
    w2t[idx] = f2h(v);
}

// ---------------- CSR build ----------------
__global__ void k_hist(const int* __restrict__ ei, int* __restrict__ cnt) {
    int e = blockIdx.x * blockDim.x + threadIdx.x;
    if (e < EE) atomicAdd(&cnt[ei[EE + e]], 1);
}

__global__ __launch_bounds__(1024) void k_scan(const int* __restrict__ cnt,
                                               int* __restrict__ row_off,
                                               int* __restrict__ cursor) {
    __shared__ int lds[1024];
    int t = threadIdx.x;
    int base = t * 16;
    int local[16];
    int total = 0;
    #pragma unroll
    for (int i = 0; i < 16; ++i) { local[i] = cnt[base + i]; total += local[i]; }
    lds[t] = total;
    __syncthreads();
    for (int off = 1; off < 1024; off <<= 1) {
        int v = (t >= off) ? lds[t - off] : 0;
        __syncthreads();
        lds[t] += v;
        __syncthreads();
    }
    int run = lds[t] - total;
    #pragma unroll
    for (int i = 0; i < 16; ++i) {
        row_off[base + i] = run;
        cursor[base + i]  = run;
        run += local[i];
    }
    if (t == 0) row_off[NN] = EE;
}

__global__ void k_fill(const int* __restrict__ ei, const int* __restrict__ eattr,
                       int* __restrict__ cursor, int* __restrict__ packed) {
    int e = blockIdx.x * blockDim.x + threadIdx.x;
    if (e >= EE) return;
    int d  = ei[EE + e];
    int s  = ei[e];
    int a0 = eattr[2*e], a1 = eattr[2*e + 1];
    int pos = atomicAdd(&cursor[d], 1);
    packed[pos] = s | ((a0*3 + a1) << 16);
}

// ---------------- per-node gather aggregation (4x unroll, float2 comb reads) ----------------
__global__ __launch_bounds__(256) void k_aggregate(const int* __restrict__ row_off,
                                                   const int* __restrict__ packed,
                                                   const u16* __restrict__ hF,
                                                   const float* __restrict__ E1,
                                                   const float* __restrict__ E2,
                                                   u16* __restrict__ agg) {
    __shared__ float comb[10 * EMB];
    int tid = threadIdx.x;
    for (int idx = tid; idx < 10 * EMB; idx += 256) {
        int r = idx / EMB, c = idx % EMB;
        comb[idx] = (r < 9) ? (E1[(r/3)*EMB + c] + E2[(r%3)*EMB + c])
                            : (E1[4*EMB + c]     + E2[0*EMB + c]);
    }
    __syncthreads();

    int wv = tid >> 6, lane = tid & 63;
    int c0 = lane, c1 = lane + 64, c2 = lane + 128;   // u32 chunk indices
    bool a2 = (c2 < 150);          // c0,c1 always active data
    bool w2r = (c2 < 160);         // c2 within row (chunks 150..159 = zero pad)

    int n = blockIdx.x * 4 + wv;
    float x0, y0, x1, y1, x2 = 0.f, y2 = 0.f;
    {   // self-loop init: h[n] + comb[9]
        const u32* hn = (const u32*)(hF + (size_t)n*KP1);
        const float* c9 = comb + 9*EMB;
        f16x2 v0 = __builtin_bit_cast(f16x2, hn[c0]);
        f16x2 v1 = __builtin_bit_cast(f16x2, hn[c1]);
        f32x2 t0 = *(const f32x2*)(c9 + 2*c0);
        f32x2 t1 = *(const f32x2*)(c9 + 2*c1);
        x0 = (float)v0.x + t0.x;  y0 = (float)v0.y + t0.y;
        x1 = (float)v1.x + t1.x;  y1 = (float)v1.y + t1.y;
        if (a2) {
            f16x2 v2 = __builtin_bit_cast(f16x2, hn[c2]);
            f32x2 t2 = *(const f32x2*)(c9 + 2*c2);
            x2 = (float)v2.x + t2.x;  y2 = (float)v2.y + t2.y;
        }
    }
    int j0 = row_off[n], j1 = row_off[n+1];
    int j = j0;
    for (; j + 3 < j1; j += 4) {       // 4x unroll: more outstanding gathers
        int pA = packed[j],   pB = packed[j+1];
        int pC = packed[j+2], pD = packed[j+3];
        const u32* hA = (const u32*)(hF + (size_t)(pA & 0xFFFF)*KP1);
        const u32* hB = (const u32*)(hF + (size_t)(pB & 0xFFFF)*KP1);
        const u32* hC = (const u32*)(hF + (size_t)(pC & 0xFFFF)*KP1);
        const u32* hD = (const u32*)(hF + (size_t)(pD & 0xFFFF)*KP1);
        const float* cA = comb + (pA >> 16)*EMB;
        const float* cB = comb + (pB >> 16)*EMB;
        const float* cC = comb + (pC >> 16)*EMB;
        const float* cD = comb + (pD >> 16)*EMB;
        u32 rA0 = hA[c0], rA1 = hA[c1], rB0 = hB[c0], rB1 = hB[c1];
        u32 rC0 = hC[c0], rC1 = hC[c1], rD0 = hD[c0], rD1 = hD[c1];
        u32 rA2 = 0, rB2 = 0, rC2 = 0, rD2 = 0;
        if (a2) { rA2 = hA[c2]; rB2 = hB[c2]; rC2 = hC[c2]; rD2 = hD[c2]; }
        f16x2 v; f32x2 t;
        v = __builtin_bit_cast(f16x2, rA0); t = *(const f32x2*)(cA + 2*c0); x0 += (float)v.x + t.x; y0 += (float)v.y + t.y;
        v = __builtin_bit_cast(f16x2, rA1); t = *(const f32x2*)(cA + 2*c1); x1 += (float)v.x + t.x; y1 += (float)v.y + t.y;
        v = __builtin_bit_cast(f16x2, rB0); t = *(const f32x2*)(cB + 2*c0); x0 += (float)v.x + t.x; y0 += (float)v.y + t.y;
        v = __builtin_bit_cast(f16x2, rB1); t = *(const f32x2*)(cB + 2*c1); x1 += (float)v.x + t.x; y1 += (float)v.y + t.y;
        v = __builtin_bit_cast(f16x2, rC0); t = *(const f32x2*)(cC + 2*c0); x0 += (float)v.x + t.x; y0 += (float)v.y + t.y;
        v = __builtin_bit_cast(f16x2, rC1); t = *(const f32x2*)(cC + 2*c1); x1 += (float)v.x + t.x; y1 += (float)v.y + t.y;
        v = __builtin_bit_cast(f16x2, rD0); t = *(const f32x2*)(cD + 2*c0); x0 += (float)v.x + t.x; y0 += (float)v.y + t.y;
        v = __builtin_bit_cast(f16x2, rD1); t = *(const f32x2*)(cD + 2*c1); x1 += (float)v.x + t.x; y1 += (float)v.y + t.y;
        if (a2) {
            v = __builtin_bit_cast(f16x2, rA2); t = *(const f32x2*)(cA + 2*c2); x2 += (float)v.x + t.x; y2 += (float)v.y + t.y;
            v = __builtin_bit_cast(f16x2, rB2); t = *(const f32x2*)(cB + 2*c2); x2 += (float)v.x + t.x; y2 += (float)v.y + t.y;
            v = __builtin_bit_cast(f16x2, rC2); t = *(const f32x2*)(cC + 2*c2); x2 += (float)v.x + t.x; y2 += (float)v.y + t.y;
            v = __builtin_bit_cast(f16x2, rD2); t = *(const f32x2*)(cD + 2*c2); x2 += (float)v.x + t.x; y2 += (float)v.y + t.y;
        }
    }
    for (; j < j1; ++j) {
        int pA = packed[j];
        const u32* hA = (const u32*)(hF + (size_t)(pA & 0xFFFF)*KP1);
        const float* cA = comb + (pA >> 16)*EMB;
        f16x2 v; f32x2 t;
        v = __builtin_bit_cast(f16x2, hA[c0]); t = *(const f32x2*)(cA + 2*c0); x0 += (float)v.x + t.x; y0 += (float)v.y + t.y;
        v = __builtin_bit_cast(f16x2, hA[c1]); t = *(const f32x2*)(cA + 2*c1); x1 += (float)v.x + t.x; y1 += (float)v.y + t.y;
        if (a2) {
            v = __builtin_bit_cast(f16x2, hA[c2]); t = *(const f32x2*)(cA + 2*c2); x2 += (float)v.x + t.x; y2 += (float)v.y + t.y;
        }
    }
    u32* ao = (u32*)(agg + (size_t)n*KP1);
    ao[c0] = packh2(x0, y0);
    ao[c1] = packh2(x1, y1);
    if (w2r) ao[c2] = a2 ? packh2(x2, y2) : 0u;   // chunks [128,160) only
}

// ---------------- f16 MFMA GEMM: C = op(A @ Bt^T + bias), BK=64, XCD swizzle ----
// STATS: fuse per-column BN partial sums (LDS 8-contributor reduce + 1 atomic/col).
// When !STATS and sums!=nullptr, one block zeroes sums/sumsq for the NEXT kernel.
template<int BLKN, bool RELU, bool OUTF16, bool STATS>
__global__ __launch_bounds__(256) void k_mgemm(const u16* __restrict__ A,
                                               const u16* __restrict__ Bt,
                                               const float* __restrict__ bias, int nbias,
                                               void* __restrict__ Cout, int ldc, int ncols,
                                               int KP,
                                               float* __restrict__ sums,
                                               float* __restrict__ sumsq) {
    constexpr int BW = BLKN / 2;
    constexpr int NF = BW / 16;
    __shared__ u16 As[128 * 64];
    __shared__ u16 Bs[BLKN * 64];
    __shared__ float red[STATS ? BLKN * 16 : 1];
    int tid  = threadIdx.x;
    int wv   = tid >> 6, lane = tid & 63;
    int wr   = wv >> 1,  wc   = wv & 1;

    // XCD-aware swizzle of the linear block id (nwg % 8 == 0 -> bijective).
    int lin = blockIdx.y * gridDim.x + blockIdx.x;
    int nwg = gridDim.x * gridDim.y;
    int cpx = nwg >> 3;
    int swz = (lin & 7) * cpx + (lin >> 3);
    int bx  = swz % gridDim.x, by = swz / gridDim.x;
    int m0   = by * 128, n0 = bx * BLKN;

    if (!STATS && sums != nullptr && swz == 0) {
        for (int c = tid; c < EMB; c += 256) { sums[c] = 0.f; sumsq[c] = 0.f; }
    }

    f32x4 acc[4][NF];
    f32x4 zz = {0.f, 0.f, 0.f, 0.f};
    #pragma unroll
    for (int i = 0; i < 4; ++i)
        #pragma unroll
        for (int j = 0; j < NF; ++j) acc[i][j] = zz;

    for (int k0 = 0; k0 < KP; k0 += 64) {
        #pragma unroll
        for (int s = 0; s < 4; ++s) {          // A tile: 128 rows x 8 chunks = 1024
            int c = tid + s*256;
            gload16(A + (size_t)(m0 + (c>>3))*KP + k0 + (c&7)*8, &As[c*8]);
        }
        #pragma unroll
        for (int s = 0; s < BLKN/32; ++s) {    // B tile: BLKN rows x 8 chunks
            int c = tid + s*256;
            gload16(Bt + (size_t)(n0 + (c>>3))*KP + k0 + (c&7)*8, &Bs[c*8]);
        }
        __syncthreads();

        int rA = lane & 15, kq = (lane >> 4) * 8;
        #pragma unroll
        for (int kk = 0; kk < 2; ++kk) {
            f16x8 af[4], bfr[NF];
            #pragma unroll
            for (int mf = 0; mf < 4; ++mf)
                af[mf] = ld_frag(&As[(wr*64 + mf*16 + rA) * 64 + kk*32 + kq]);
            #pragma unroll
            for (int nf = 0; nf < NF; ++nf)
                bfr[nf] = ld_frag(&Bs[(wc*BW + nf*16 + rA) * 64 + kk*32 + kq]);
            #pragma unroll
            for (int mf = 0; mf < 4; ++mf)
                #pragma unroll
                for (int nf = 0; nf < NF; ++nf)
                    acc[mf][nf] = __builtin_amdgcn_mfma_f32_16x16x32_f16(
                        af[mf], bfr[nf], acc[mf][nf], 0, 0, 0);
        }
        __syncthreads();
    }

    // epilogue: C row = (lane>>4)*4 + reg, col = lane&15
    int rq = (lane >> 4) * 4, cn = lane & 15;
    float s1v[NF], s2v[NF];
    #pragma unroll
    for (int nf = 0; nf < NF; ++nf) { s1v[nf] = 0.f; s2v[nf] = 0.f; }
    #pragma unroll
    for (int nf = 0; nf < NF; ++nf) {
        int n = n0 + wc*BW + nf*16 + cn;
        float bv = (n < nbias) ? bias[n] : 0.f;
        #pragma unroll
        for (int mf = 0; mf < 4; ++mf) {
            #pragma unroll
            for (int r = 0; r < 4; ++r) {
                int m = m0 + wr*64 + mf*16 + rq + r;
                float v = acc[mf][nf][r] + bv;
                if (RELU) v = fmaxf(v, 0.f);
                if (STATS) { s1v[nf] += v; s2v[nf] += v*v; }
                if (OUTF16) {
                    ((u16*)Cout)[(size_t)m * ldc + n] = f2h(v);
                } else {
                    if (n < ncols) ((float*)Cout)[(size_t)m * ldc + n] = v;
                }
            }
        }
    }
    if (STATS) {
        int contrib = wr*4 + (lane >> 4);      // 0..7
        #pragma unroll
        for (int nf = 0; nf < NF; ++nf) {
            int cidx = wc*BW + nf*16 + cn;     // 0..BLKN-1
            red[cidx*8 + contrib] = s1v[nf];
            red[BLKN*8 + cidx*8 + contrib] = s2v[nf];
        }
        __syncthreads();
        for (int cc = tid; cc < BLKN; cc += 256) {
            int n = n0 + cc;
            if (n < nbias) {
                float a = 0.f, b = 0.f;
                #pragma unroll
                for (int q = 0; q < 8; ++q) {
                    a += red[cc*8 + q];
                    b += red[BLKN*8 + cc*8 + q];
                }
                atomicAdd(&sums[n], a);
                atomicAdd(&sumsq[n], b);
            }
        }
    }
}

// ---------------- BN apply (mu/rs recomputed per block from sums/sumsq) ----------------
#define CH 75   // float4 chunks per 300-channel row

// layers 0..3: normalize + affine + ReLU -> f16 padded hF (pad cols never read)
__global__ __launch_bounds__(256) void k_bnapply_f16(
        const float* __restrict__ hP, const float* __restrict__ sums,
        const float* __restrict__ sumsq, const float* __restrict__ gamma,
        const float* __restrict__ beta, u16* __restrict__ hF) {
    __shared__ float smu[EMB], sga[EMB], sbe[EMB];
    int tid = threadIdx.x;
    for (int c = tid; c < EMB; c += 256) {
        float m = sums[c] * (1.f/NN);
        float v = sumsq[c] * (1.f/NN) - m*m;
        smu[c] = m;
        sga[c] = rsqrtf(v + BN_EPS) * gamma[c];
        sbe[c] = beta[c];
    }
    __syncthreads();
    const int total = NN * CH;
    for (int idx = blockIdx.x*256 + tid; idx < total; idx += gridDim.x*256) {
        int r = idx / CH, ch = idx - r*CH;
        int c = ch*4;
        f32x4 v = *(const f32x4*)(hP + (size_t)r*EMB + c);
        float o0 = fmaxf((v[0] - smu[c  ])*sga[c  ] + sbe[c  ], 0.f);
        float o1 = fmaxf((v[1] - smu[c+1])*sga[c+1] + sbe[c+1], 0.f);
        float o2 = fmaxf((v[2] - smu[c+2])*sga[c+2] + sbe[c+2], 0.f);
        float o3 = fmaxf((v[3] - smu[c+3])*sga[c+3] + sbe[c+3], 0.f);
        u32* dst = (u32*)(hF + (size_t)r*KP1) + ch*2;
        dst[0] = packh2(o0, o1);
        dst[1] = packh2(o2, o3);
    }
}

// last layer: normalize + affine (no ReLU) -> f32 out
__global__ __launch_bounds__(256) void k_bnapply_f32(
        const float* __restrict__ hP, const float* __restrict__ sums,
        const float* __restrict__ sumsq, const float* __restrict__ gamma,
        const float* __restrict__ beta, float* __restrict__ out) {
    __shared__ float smu[EMB], sga[EMB], sbe[EMB];
    int tid = threadIdx.x;
    for (int c = tid; c < EMB; c += 256) {
        float m = sums[c] * (1.f/NN);
        float v = sumsq[c] * (1.f/NN) - m*m;
        smu[c] = m;
        sga[c] = rsqrtf(v + BN_EPS) * gamma[c];
        sbe[c] = beta[c];
    }
    __syncthreads();
    const int total = NN * CH;
    for (int idx = blockIdx.x*256 + tid; idx < total; idx += gridDim.x*256) {
        int r = idx / CH, ch = idx - r*CH;
        int c = ch*4;
        f32x4 v = *(const f32x4*)(hP + (size_t)r*EMB + c);
        f32x4 o;
        o[0] = (v[0] - smu[c  ])*sga[c  ] + sbe[c  ];
        o[1] = (v[1] - smu[c+1])*sga[c+1] + sbe[c+1];
        o[2] = (v[2] - smu[c+2])*sga[c+2] + sbe[c+2];
        o[3] = (v[3] - smu[c+3])*sga[c+3] + sbe[c+3];
        *(f32x4*)(out + (size_t)r*EMB + c) = o;
    }
}

extern "C" void kernel_launch(void* const* d_in, const int* in_sizes, int n_in,
                              void* d_out, int out_size, void* d_ws, size_t ws_size,
                              hipStream_t stream) {
    const int*   x     = (const int*)d_in[0];
    const int*   ei    = (const int*)d_in[1];
    const int*   eattr = (const int*)d_in[2];
    const float* ta    = (const float*)d_in[3];
    const float* td    = (const float*)d_in[4];
    const float* tc    = (const float*)d_in[5];
    const float* th    = (const float*)d_in[6];
    const float* tar   = (const float*)d_in[7];
    const float* tch   = (const float*)d_in[8];
    const float* W1    = (const float*)d_in[9];
    const float* b1    = (const float*)d_in[10];
    const float* W2    = (const float*)d_in[11];
    const float* b2    = (const float*)d_in[12];
    const float* ee1   = (const float*)d_in[13];
    const float* ee2   = (const float*)d_in[14];
    const float* gam   = (const float*)d_in[15];
    const float* bet   = (const float*)d_in[16];
    float* out = (float*)d_out;

    char* ws = (char*)d_ws;
    float* hP   = (float*)ws;                         ws += (size_t)NN*EMB*4;   // pre-BN h (f32)
    u16*   hF   = (u16*)ws;                           ws += (size_t)NN*KP1*2;   // post-BN h (f16)
    u16*   aggF = (u16*)ws;                           ws += (size_t)NN*KP1*2;
    u16*   t    = (u16*)ws;                           ws += (size_t)NN*N1*2;
    u16*   w1t  = (u16*)ws;                           ws += (size_t)NL*N1*KP1*2;
    u16*   w2t  = (u16*)ws;                           ws += (size_t)NL*N2*KP2*2;
    float* stat = (float*)ws;                         ws += 4096;
    int*   cnt  = (int*)ws;                           ws += (size_t)NN*4;
    int*   row_off = (int*)ws;                        ws += (size_t)(NN+1)*4 + 60;
    int*   cursor  = (int*)ws;                        ws += (size_t)NN*4;
    int*   packed  = (int*)ws;
    float* sums = stat, *sumsq = stat+300;

    // ---- once per call: weight f16 transpose, CSR build, init h ----
    k_cvt_w1<<<(NL*N1*KP1 + 255)/256, 256, 0, stream>>>(W1, w1t);
    k_cvt_w2<<<(NL*N2*KP2 + 255)/256, 256, 0, stream>>>(W2, w2t);
    hipMemsetAsync(cnt, 0, (size_t)NN*4, stream);
    k_hist<<<EE/256, 256, 0, stream>>>(ei, cnt);
    k_scan<<<1, 1024, 0, stream>>>(cnt, row_off, cursor);
    k_fill<<<EE/256, 256, 0, stream>>>(ei, eattr, cursor, packed);
    k_init_h<<<NN, KP1, 0, stream>>>(x, ta, td, tc, th, tar, tch, hF);

    for (int l = 0; l < NL; ++l) {
        k_aggregate<<<4096, 256, 0, stream>>>(row_off, packed, hF,
                                              ee1 + (size_t)l*6*EMB,
                                              ee2 + (size_t)l*3*EMB, aggF);
        // GEMM1: 128x128 tiles, grid (5,128); swizzled block 0 zeroes stats.
        k_mgemm<128, true, true, false><<<dim3(N1/128, NN/128), 256, 0, stream>>>(
            aggF, w1t + (size_t)l*N1*KP1, b1 + (size_t)l*H2, H2,
            t, N1, N1, KP1, sums, sumsq);
        // GEMM2: 128x64 tiles, grid (5,128); fused BN stats.
        k_mgemm<64, false, false, true><<<dim3(N2/64, NN/128), 256, 0, stream>>>(
            t, w2t + (size_t)l*N2*KP2, b2 + (size_t)l*EMB, EMB,
            hP, EMB, EMB, KP2, sums, sumsq);
        if (l < NL-1)
            k_bnapply_f16<<<2048, 256, 0, stream>>>(hP, sums, sumsq,
                                                    gam + (size_t)l*EMB, bet + (size_t)l*EMB, hF);
        else
            k_bnapply_f32<<<2048, 256, 0, stream>>>(hP, sums, sumsq,
                                                    gam + (size_t)l*EMB, bet + (size_t)l*EMB, out);
    }
}